// Round 10
// baseline (102.082 us; speedup 1.0000x reference)
//
#include <hip/hip_runtime.h>
#include <hip/hip_bf16.h>
#include <stdint.h>

// ---------------- helpers ----------------
__device__ __forceinline__ float bf2f(unsigned short u) {
    unsigned int x = ((unsigned int)u) << 16;
    return __uint_as_float(x);
}
__device__ __forceinline__ unsigned short f2bf(float f) {
    unsigned int x = __float_as_uint(f);
    unsigned int lsb = (x >> 16) & 1u;
    x += 0x7fffu + lsb;           // round-to-nearest-even
    return (unsigned short)(x >> 16);
}
__device__ __forceinline__ unsigned int pack2bf(float lo, float hi) {
    return (unsigned int)f2bf(lo) | ((unsigned int)f2bf(hi) << 16);
}
// unpack one u32 = 2 bf16 into floats
__device__ __forceinline__ float bflo(unsigned int u) { return __uint_as_float(u << 16); }
__device__ __forceinline__ float bfhi(unsigned int u) { return __uint_as_float(u & 0xffff0000u); }
__device__ __forceinline__ float loadF(const void* p, int i, int isbf) {
    return isbf ? bf2f(((const unsigned short*)p)[i]) : ((const float*)p)[i];
}

// ---------------- init: zero bcnt + sentinel z rows + dtype flags ----------------
// flags[0] = floats bf16(1)/f32(0); flags[1] = edge_index int64(1)/int32(0)
__global__ void k_init(const void* x, const void* eidx, int* flags, int* bcnt, int B,
                       unsigned int* z0s, unsigned int* z1s) {
    int t = threadIdx.x;   // 1024
    for (int b = t; b < B; b += blockDim.x) bcnt[b] = 0;
    if (t < 8) z0s[t] = 0;                       // sentinel row (16 bf16 = 8 u32)
    else if (t < 16) z1s[t - 8] = 0;
    if (t < 64) {
        const unsigned short* u = (const unsigned short*)x;
        float a = fabsf(bf2f(u[2 * t]));
        bool ok = (a == 0.0f) || (a > 1e-30f && a < 1e4f);
        unsigned long long mbf = __ballot(ok);
        if (t == 0) flags[0] = (mbf == ~0ULL) ? 1 : 0;
    } else if (t < 128) {
        int l = t - 64;
        const int* ip = (const int*)eidx;
        unsigned long long mi64 = __ballot(ip[2 * l + 1] == 0);
        if (l == 0) flags[1] = (mi64 == ~0ULL) ? 1 : 0;
    }
}

// ---------------- fused: edge binning (blocks 0..G-1) + consts (block G) -------
// Binning: bucket = dst >> rsh (R=128). Packed word = (src << rsh) | (dst & R-1).
// Consts: M = W1^3 W2 ; cvecs = {g3=b1W1^2W2, g2=b1W1W2, g1=b1W2, b2}
#define TS 68
__global__ void k_bin(const void* eidx, int E, int rsh, int B, int cap,
                      unsigned int* bins, int* bcnt, const int* flags,
                      const void* W1, const void* b1, const void* W2, const void* b2,
                      float* M, float* cvecs, int nbin) {
    if ((int)blockIdx.x == nbin) {   // ---- consts block ----
        __shared__ float A[64 * 64];
        __shared__ float T1[64 * TS];
        __shared__ float T2[64 * TS];
        __shared__ float B2s[64 * 16];
        __shared__ float bv[64], bw1[64], bw2[64];
        int bf = flags[0];
        int t = threadIdx.x;   // 512 threads; use 256
        if (t < 256) {
            for (int i = t; i < 4096; i += 256) A[i] = loadF(W1, i, bf);
            for (int i = t; i < 1024; i += 256) B2s[i] = loadF(W2, i, bf);
            if (t < 64) bv[t] = loadF(b1, t, bf);
        }
        __syncthreads();
        if (t < 256) {
            const int i0 = (t >> 4) * 4;
            const int j0 = (t & 15) * 4;
            {   // T1 = A @ A
                float acc[4][4] = {};
#pragma unroll 8
                for (int k = 0; k < 64; ++k) {
                    float a0 = A[(i0 + 0) * 64 + k];
                    float a1 = A[(i0 + 1) * 64 + k];
                    float a2 = A[(i0 + 2) * 64 + k];
                    float a3 = A[(i0 + 3) * 64 + k];
                    float4 bq = *(const float4*)&A[k * 64 + j0];
                    acc[0][0] += a0 * bq.x; acc[0][1] += a0 * bq.y; acc[0][2] += a0 * bq.z; acc[0][3] += a0 * bq.w;
                    acc[1][0] += a1 * bq.x; acc[1][1] += a1 * bq.y; acc[1][2] += a1 * bq.z; acc[1][3] += a1 * bq.w;
                    acc[2][0] += a2 * bq.x; acc[2][1] += a2 * bq.y; acc[2][2] += a2 * bq.z; acc[2][3] += a2 * bq.w;
                    acc[3][0] += a3 * bq.x; acc[3][1] += a3 * bq.y; acc[3][2] += a3 * bq.z; acc[3][3] += a3 * bq.w;
                }
#pragma unroll
                for (int ii = 0; ii < 4; ++ii)
                    *(float4*)&T1[(i0 + ii) * TS + j0] = make_float4(acc[ii][0], acc[ii][1], acc[ii][2], acc[ii][3]);
            }
            if (t < 64) {
                float acc = 0.f;
#pragma unroll 8
                for (int i = 0; i < 64; ++i) acc += bv[i] * A[i * 64 + t];
                bw1[t] = acc;
            }
        }
        __syncthreads();
        if (t < 256) {
            const int i0 = (t >> 4) * 4;
            const int j0 = (t & 15) * 4;
            {   // T2 = T1 @ A
                float acc[4][4] = {};
#pragma unroll 8
                for (int k = 0; k < 64; ++k) {
                    float a0 = T1[(i0 + 0) * TS + k];
                    float a1 = T1[(i0 + 1) * TS + k];
                    float a2 = T1[(i0 + 2) * TS + k];
                    float a3 = T1[(i0 + 3) * TS + k];
                    float4 bq = *(const float4*)&A[k * 64 + j0];
                    acc[0][0] += a0 * bq.x; acc[0][1] += a0 * bq.y; acc[0][2] += a0 * bq.z; acc[0][3] += a0 * bq.w;
                    acc[1][0] += a1 * bq.x; acc[1][1] += a1 * bq.y; acc[1][2] += a1 * bq.z; acc[1][3] += a1 * bq.w;
                    acc[2][0] += a2 * bq.x; acc[2][1] += a2 * bq.y; acc[2][2] += a2 * bq.z; acc[2][3] += a2 * bq.w;
                    acc[3][0] += a3 * bq.x; acc[3][1] += a3 * bq.y; acc[3][2] += a3 * bq.z; acc[3][3] += a3 * bq.w;
                }
#pragma unroll
                for (int ii = 0; ii < 4; ++ii)
                    *(float4*)&T2[(i0 + ii) * TS + j0] = make_float4(acc[ii][0], acc[ii][1], acc[ii][2], acc[ii][3]);
            }
            if (t < 64) {
                float acc = 0.f;
#pragma unroll 8
                for (int i = 0; i < 64; ++i) acc += bw1[i] * A[i * 64 + t];
                bw2[t] = acc;
            }
        }
        __syncthreads();
        if (t < 256) {
            {   // M = T2 @ B2 (64x16)
                int i = t >> 2, j0m = (t & 3) * 4;
                float4 acc = {0.f, 0.f, 0.f, 0.f};
#pragma unroll 8
                for (int k = 0; k < 64; ++k) {
                    float a = T2[i * TS + k];
                    float4 bq = *(const float4*)&B2s[k * 16 + j0m];
                    acc.x += a * bq.x; acc.y += a * bq.y; acc.z += a * bq.z; acc.w += a * bq.w;
                }
                *(float4*)&M[i * 16 + j0m] = acc;
            }
            if (t < 16) {
                float a3 = 0.f, a2 = 0.f, a1 = 0.f;
#pragma unroll 8
                for (int i = 0; i < 64; ++i) {
                    float w = B2s[i * 16 + t];
                    a3 += bw2[i] * w;
                    a2 += bw1[i] * w;
                    a1 += bv[i] * w;
                }
                cvecs[t] = a3;
                cvecs[16 + t] = a2;
                cvecs[32 + t] = a1;
                cvecs[48 + t] = loadF(b2, t, flags[0]);
            }
        }
        return;
    }
    // ---- binning blocks ----
    extern __shared__ int sh[];            // 2*B ints
    int* hist   = sh;
    int* base_s = sh + B;
    const int i64 = flags[1];
    const int t = threadIdx.x, nt = blockDim.x;
    const long long i0 = (long long)blockIdx.x * E / nbin;
    const long long i1 = (long long)(blockIdx.x + 1) * E / nbin;
    const long long* e64 = (const long long*)eidx;
    const int* e32 = (const int*)eidx;
    const int mask = (1 << rsh) - 1;

    for (int b = t; b < B; b += nt) hist[b] = 0;
    __syncthreads();
    for (long long i = i0 + t; i < i1; i += nt) {
        int d = i64 ? (int)e64[E + i] : e32[E + i];
        atomicAdd(&hist[d >> rsh], 1);
    }
    __syncthreads();
    for (int b = t; b < B; b += nt) {
        int c = hist[b];
        base_s[b] = c ? atomicAdd(&bcnt[b], c) : 0;
        hist[b] = 0;
    }
    __syncthreads();
    for (long long i = i0 + t; i < i1; i += nt) {
        int d, s;
        if (i64) { d = (int)e64[E + i]; s = (int)e64[i]; }
        else     { d = e32[E + i];     s = e32[i]; }
        int b = d >> rsh;
        int pos = base_s[b] + atomicAdd(&hist[b], 1);
        if (pos >= cap) pos = cap - 1;     // paranoia guard
        bins[(size_t)b * cap + pos] = ((unsigned int)s << rsh) | (unsigned int)(d & mask);
    }
}

// ---------------- per-bucket CSR build: padded colb + packed meta ----------------
// Each node's adjacency padded to a multiple of 4 with sentinel index n
// (z[n] == 0). meta[v] = { rstart, len, dinv_bits, 0 }; rstart 4-aligned.
__global__ void k_csr(const unsigned int* bins, const int* bcnt, int cap, int capP,
                      int rsh, int n, int* colb, int4* meta) {
    __shared__ int dh[128], db[128], pl[128], ch[128];
    const int R = 1 << rsh;                // 128
    const int b = blockIdx.x, t = threadIdx.x, nt = blockDim.x;
    const int mask = R - 1;
    for (int r = t; r < R; r += nt) { dh[r] = 0; ch[r] = 0; }
    __syncthreads();
    int cnt = bcnt[b]; if (cnt > cap) cnt = cap;
    const unsigned int* eb = bins + (size_t)b * cap;
    for (int e = t; e < cnt; e += nt)
        atomicAdd(&dh[eb[e] & mask], 1);
    __syncthreads();
    if (t < R) { pl[t] = (dh[t] + 3) & ~3; db[t] = pl[t]; }
    __syncthreads();
    for (int off = 1; off < R; off <<= 1) {
        int add = 0;
        if (t < R && t >= off) add = db[t - off];
        __syncthreads();
        if (t < R) db[t] += add;
        __syncthreads();
    }
    const int v0 = b << rsh;
    const int gbase = b * capP;
    if (t < R) {
        int v = v0 + t;
        if (v < n) {
            int len = dh[t];
            float dv = rsqrtf((float)(len + 1));
            int rs = gbase + db[t] - pl[t];
            meta[v] = make_int4(rs, len, __float_as_int(dv), 0);
            for (int p = len; p < pl[t]; ++p) colb[rs + p] = n;   // sentinel pad
        }
    }
    __syncthreads();
    for (int e = t; e < cnt; e += nt) {
        unsigned int w = eb[e];
        int r = w & mask;
        int pos = (db[r] - pl[r]) + atomicAdd(&ch[r], 1);
        colb[gbase + pos] = (int)(w >> rsh);
    }
}

// ---------------- z0 = bf16( dinv * (x @ M) ) ----------------
__global__ void k_xm(const void* x, const float* M, const int4* meta,
                     unsigned short* z0, int n, const int* flags) {
    __shared__ float Ms[64 * 16];
    __shared__ float xs[16 * 64];
    int bf = flags[0];
    int t = threadIdx.x;   // 256
    ((float4*)Ms)[t] = ((const float4*)M)[t];
    int base = blockIdx.x * 16;
    if (!bf) {
        int row = base + (t >> 4);
        float4 v = make_float4(0.f, 0.f, 0.f, 0.f);
        if (row < n) v = ((const float4*)x)[base * 16 + t];
        ((float4*)xs)[t] = v;
    } else {
        for (int k = t; k < 1024; k += 256) {
            int r = k >> 6, cc = k & 63;
            int row = base + r;
            xs[k] = (row < n) ? bf2f(((const unsigned short*)x)[row * 64 + cc]) : 0.f;
        }
    }
    __syncthreads();
    int r = t >> 4, c = t & 15;
    int row = base + r;
    if (row < n) {
        float acc = 0.f;
#pragma unroll
        for (int k = 0; k < 64; ++k) acc += xs[r * 64 + k] * Ms[k * 16 + c];
        float dv = __int_as_float(meta[row].z);
        z0[row * 16 + c] = f2bf(dv * acc);   // bf16 z-space
    }
}

// ---------------- pull prop: 2 lanes/node, int4 colb, 16B bf16 gathers --------
// sum = z[v] + sum_{s in N(v)+pad} z[s]   (sentinel row == 0)
// non-final: zout = bf16(dinv^2*sum + dinv*cvec) ; final: yout = dinv*sum + cvec
__global__ void k_prop(const unsigned short* zin, void* yout, const int4* meta,
                       const int* colb, const float* cvec,
                       int n, int is_final, const int* flags) {
    int tid = blockIdx.x * blockDim.x + threadIdx.x;
    int v = tid >> 1, h = tid & 1;         // lane h covers channels [h*8, h*8+8)
    if (v >= n) return;
    int4 m = meta[v];                      // {rstart, len, dinv_bits, 0}
    int beg = m.x, len = m.y;
    int padlen = (len + 3) & ~3;
    // acc[8] from self row
    int4 sw = *(const int4*)&zin[(size_t)v * 16 + h * 8];
    float a0 = bflo((unsigned)sw.x), a1 = bfhi((unsigned)sw.x);
    float a2 = bflo((unsigned)sw.y), a3 = bfhi((unsigned)sw.y);
    float a4 = bflo((unsigned)sw.z), a5 = bfhi((unsigned)sw.z);
    float a6 = bflo((unsigned)sw.w), a7 = bfhi((unsigned)sw.w);
    for (int j = beg; j < beg + padlen; j += 4) {
        int4 cc = *(const int4*)&colb[j];
        int4 za = *(const int4*)&zin[(size_t)cc.x * 16 + h * 8];
        int4 zb = *(const int4*)&zin[(size_t)cc.y * 16 + h * 8];
        int4 zc = *(const int4*)&zin[(size_t)cc.z * 16 + h * 8];
        int4 zd = *(const int4*)&zin[(size_t)cc.w * 16 + h * 8];
        a0 += (bflo((unsigned)za.x) + bflo((unsigned)zb.x)) + (bflo((unsigned)zc.x) + bflo((unsigned)zd.x));
        a1 += (bfhi((unsigned)za.x) + bfhi((unsigned)zb.x)) + (bfhi((unsigned)zc.x) + bfhi((unsigned)zd.x));
        a2 += (bflo((unsigned)za.y) + bflo((unsigned)zb.y)) + (bflo((unsigned)zc.y) + bflo((unsigned)zd.y));
        a3 += (bfhi((unsigned)za.y) + bfhi((unsigned)zb.y)) + (bfhi((unsigned)zc.y) + bfhi((unsigned)zd.y));
        a4 += (bflo((unsigned)za.z) + bflo((unsigned)zb.z)) + (bflo((unsigned)zc.z) + bflo((unsigned)zd.z));
        a5 += (bfhi((unsigned)za.z) + bfhi((unsigned)zb.z)) + (bfhi((unsigned)zc.z) + bfhi((unsigned)zd.z));
        a6 += (bflo((unsigned)za.w) + bflo((unsigned)zb.w)) + (bflo((unsigned)zc.w) + bflo((unsigned)zd.w));
        a7 += (bfhi((unsigned)za.w) + bfhi((unsigned)zb.w)) + (bfhi((unsigned)zc.w) + bfhi((unsigned)zd.w));
    }
    float dv = __int_as_float(m.z);
    float sa = is_final ? dv : dv * dv;
    float sb = is_final ? 1.0f : dv;
    float4 cv0 = *(const float4*)&cvec[h * 8];
    float4 cv1 = *(const float4*)&cvec[h * 8 + 4];
    float r0 = sa * a0 + sb * cv0.x;
    float r1 = sa * a1 + sb * cv0.y;
    float r2 = sa * a2 + sb * cv0.z;
    float r3 = sa * a3 + sb * cv0.w;
    float r4 = sa * a4 + sb * cv1.x;
    float r5 = sa * a5 + sb * cv1.y;
    float r6 = sa * a6 + sb * cv1.z;
    float r7 = sa * a7 + sb * cv1.w;
    if (is_final) {
        if (flags[0]) {
            int4 ov;
            ov.x = (int)pack2bf(r0, r1);
            ov.y = (int)pack2bf(r2, r3);
            ov.z = (int)pack2bf(r4, r5);
            ov.w = (int)pack2bf(r6, r7);
            *(int4*)&((unsigned short*)yout)[(size_t)v * 16 + h * 8] = ov;
        } else {
            float* o = &((float*)yout)[(size_t)v * 16 + h * 8];
            *(float4*)o = make_float4(r0, r1, r2, r3);
            *(float4*)(o + 4) = make_float4(r4, r5, r6, r7);
        }
    } else {
        int4 ov;
        ov.x = (int)pack2bf(r0, r1);
        ov.y = (int)pack2bf(r2, r3);
        ov.z = (int)pack2bf(r4, r5);
        ov.w = (int)pack2bf(r6, r7);
        *(int4*)&((unsigned short*)yout)[(size_t)v * 16 + h * 8] = ov;
    }
}

// ---------------- launch ----------------
extern "C" void kernel_launch(void* const* d_in, const int* in_sizes, int n_in,
                              void* d_out, int out_size, void* d_ws, size_t ws_size,
                              hipStream_t stream) {
    const void* x  = d_in[0];
    const void* W1 = d_in[1];
    const void* b1 = d_in[2];
    const void* W2 = d_in[3];
    const void* b2 = d_in[4];
    const void* ei = d_in[5];

    const int n = in_sizes[0] / 64;       // 100000
    const int E = in_sizes[5] / 2;        // 1000000

    const int rsh = 7;
    const int B = (n + (1 << rsh) - 1) >> rsh;       // 782
    const int avg = E / B;
    int cap = avg + avg / 4 + 128;                    // mean + ~12 sigma slack
    cap = (cap + 31) & ~31;
    const int capP = cap + 512;                       // padded colb stride (mult of 4)

    char* base = (char*)d_ws;
    size_t off = 0;
    auto carve = [&](size_t bytes) -> void* {
        void* r = base + off;
        off = (off + bytes + 255) & ~(size_t)255;
        return r;
    };
    int*            flags  = (int*)carve(8);
    int*            bcnt   = (int*)carve((size_t)B * 4);
    unsigned int*   bins   = (unsigned int*)carve((size_t)B * cap * 4);
    int*            colb   = (int*)carve((size_t)B * capP * 4);
    int4*           meta   = (int4*)carve((size_t)n * 16);
    float*          Mm     = (float*)carve(1024 * 4);
    float*          cvecs  = (float*)carve(64 * 4);
    unsigned short* z0     = (unsigned short*)carve(((size_t)n + 1) * 16 * 2);
    unsigned short* z1     = (unsigned short*)carve(((size_t)n + 1) * 16 * 2);
    (void)ws_size; (void)n_in; (void)out_size;

    const int nbin = 240;
    k_init<<<1, 1024, 0, stream>>>(x, ei, flags, bcnt, B,
                                   (unsigned int*)&z0[(size_t)n * 16],
                                   (unsigned int*)&z1[(size_t)n * 16]);
    k_bin<<<nbin + 1, 512, (size_t)2 * B * 4, stream>>>(ei, E, rsh, B, cap, bins, bcnt,
                                                        flags, W1, b1, W2, b2, Mm, cvecs, nbin);
    k_csr<<<B, 256, 0, stream>>>(bins, bcnt, cap, capP, rsh, n, colb, meta);
    k_xm<<<(n + 15) / 16, 256, 0, stream>>>(x, Mm, meta, z0, n, flags);

    const int pgrid = (n * 2 + 255) / 256;
    k_prop<<<pgrid, 256, 0, stream>>>(z0, z1, meta, colb, cvecs + 0,  n, 0, flags);
    k_prop<<<pgrid, 256, 0, stream>>>(z1, z0, meta, colb, cvecs + 16, n, 0, flags);
    k_prop<<<pgrid, 256, 0, stream>>>(z0, z1, meta, colb, cvecs + 32, n, 0, flags);
    k_prop<<<pgrid, 256, 0, stream>>>(z1, d_out, meta, colb, cvecs + 48, n, 1, flags);
}